// Round 4
// baseline (91.347 us; speedup 1.0000x reference)
//
#include <hip/hip_runtime.h>

// Problem constants (fixed by reference)
constexpr int B = 4, T = 8, V = 256, F = 64;
constexpr int BT = B * T;            // 32 (b,t) slices
constexpr int CHUNK = 4;             // rows of i per block
constexpr int NCHUNK = V / CHUNK;    // 64 -> grid = 32*64 = 2048 blocks (8 blocks/CU)

// Single regular kernel. Block = (bt, 4-row chunk). Thread tid owns column j=tid.
// score(i,j) = sum_f |x_i[f]-x_j[f]|*a[f] is SYMMETRIC, so
// denom[i] (= column-i sum in the reference) equals the row-i sum, which this
// block computes in full -> denominator is a block-level reduction. No grid
// sync, no atomics, no workspace. A block must own ALL 256 j's for its rows
// (denominator locality), so rows/block is the only tunable: CHUNK=4 gives
// grid=2048 = 8 blocks/CU = 32 waves/CU (100% occupancy at VGPR=56).
__global__ __launch_bounds__(256)
void gl_fused(const float* __restrict__ X, const float* __restrict__ A,
              float* __restrict__ OUT)
{
    const int tid = threadIdx.x;           // column j
    const int bt  = blockIdx.x / NCHUNK;
    const int ic  = blockIdx.x % NCHUNK;
    const int i0  = ic * CHUNK;

    const float* xbt = X + (size_t)bt * V * F;   // [256][64] tile

    __shared__ float sxi[CHUNK * F];       // 1 KB: the CHUNK "i" rows
    __shared__ float wpart[4][CHUNK];      // per-wave partial row sums
    __shared__ float rden[CHUNK];          // reciprocal denominators

    // stage chunk rows into LDS: CHUNK*F = 256 floats, first 64 threads x float4
    if (tid < CHUNK * F / 4)
        reinterpret_cast<float4*>(sxi)[tid] =
            reinterpret_cast<const float4*>(xbt + (size_t)i0 * F)[tid];

    // a -> uniform address, compiler scalarizes to SGPRs
    float af[F];
#pragma unroll
    for (int k = 0; k < F / 4; ++k) {
        const float4 v = reinterpret_cast<const float4*>(A)[k];
        af[4*k+0] = v.x; af[4*k+1] = v.y; af[4*k+2] = v.z; af[4*k+3] = v.w;
    }

    __syncthreads();

    float acc[CHUNK];
#pragma unroll
    for (int r = 0; r < CHUNK; ++r) acc[r] = 0.0f;

    // stream own column in float4 chunks; CHUNK independent fma chains for ILP.
    // srow addresses are wave-uniform -> LDS broadcast b128 reads, conflict-free.
    // f-summation order identical to previous rounds (bit-exact numerics).
    const float4* colp = reinterpret_cast<const float4*>(xbt + (size_t)tid * F);
#pragma unroll
    for (int k = 0; k < F / 4; ++k) {
        const float4 xv = colp[k];
#pragma unroll
        for (int r = 0; r < CHUNK; ++r) {
            const float4 sr = *reinterpret_cast<const float4*>(&sxi[r * F + 4 * k]);
            float s = acc[r];
            s = fmaf(fabsf(xv.x - sr.x), af[4*k+0], s);
            s = fmaf(fabsf(xv.y - sr.y), af[4*k+1], s);
            s = fmaf(fabsf(xv.z - sr.z), af[4*k+2], s);
            s = fmaf(fabsf(xv.w - sr.w), af[4*k+3], s);
            acc[r] = s;
        }
    }

    float tmp[CHUNK];
#pragma unroll
    for (int r = 0; r < CHUNK; ++r)
        tmp[r] = __expf(fmaxf(acc[r], 0.0f));

    // block reduction: row sum = denominator (symmetry)
    const int lane = tid & 63;
    const int wv   = tid >> 6;
#pragma unroll
    for (int r = 0; r < CHUNK; ++r) {
        float v = tmp[r];
        v += __shfl_xor(v, 32);
        v += __shfl_xor(v, 16);
        v += __shfl_xor(v, 8);
        v += __shfl_xor(v, 4);
        v += __shfl_xor(v, 2);
        v += __shfl_xor(v, 1);
        if (lane == 0) wpart[wv][r] = v;
    }
    __syncthreads();
    if (tid < CHUNK) {
        const float d = wpart[0][tid] + wpart[1][tid] + wpart[2][tid] + wpart[3][tid];
        rden[tid] = 1.0f / d;
    }
    __syncthreads();

    // S[bt, i0+r, tid] = tmp[r] / denom[i0+r]; consecutive tids -> coalesced
    float* obase = OUT + (((size_t)bt * V + i0) * V) + tid;
#pragma unroll
    for (int r = 0; r < CHUNK; ++r)
        obase[(size_t)r * V] = tmp[r] * rden[r];
}

extern "C" void kernel_launch(void* const* d_in, const int* in_sizes, int n_in,
                              void* d_out, int out_size, void* d_ws, size_t ws_size,
                              hipStream_t stream)
{
    const float* X = (const float*)d_in[0];   // [B,T,V,F] fp32
    const float* A = (const float*)d_in[1];   // [F,1]     fp32
    float* OUT = (float*)d_out;               // [B,T,V,V] fp32

    dim3 grid(BT * NCHUNK), block(256);
    gl_fused<<<grid, block, 0, stream>>>(X, A, OUT);
}

// Round 5
// 72.236 us; speedup vs baseline: 1.2646x; 1.2646x over previous
//
#include <hip/hip_runtime.h>

// Problem constants (fixed by reference)
constexpr int B = 4, T = 8, V = 256, F = 64;
constexpr int BT = B * T;            // 32 (b,t) slices
constexpr int CHUNK = 8;             // rows of i per block (R3 sweet spot)
constexpr int NCHUNK = V / CHUNK;    // 32 -> grid = 32*32 = 1024 blocks (4 blocks/CU)

// Block = (bt, 8-row chunk). Thread tid owns column j=tid.
// score(i,j) = sum_f |x_i[f]-x_j[f]|*a[f] is SYMMETRIC, so denom[i]
// (= column-i sum in the reference) equals the row-i sum -> block-local
// reduction, no grid sync / atomics / workspace.
//
// R5 change: row data (x_i) is read through WAVE-UNIFORM global addresses so
// the compiler scalarizes to s_load_dwordx4 (scalar pipe + scalar cache)
// instead of staging through LDS (R3/R4 issued 128 ds_read_b128/thread on the
// LDS pipe + a staging barrier). Inner loop is pure VALU; LDS is used only
// for the small cross-wave reduction.
__global__ __launch_bounds__(256)
void gl_fused(const float* __restrict__ X, const float* __restrict__ A,
              float* __restrict__ OUT)
{
    const int tid = threadIdx.x;           // column j
    const int bt  = blockIdx.x / NCHUNK;
    const int ic  = blockIdx.x % NCHUNK;
    const int i0  = ic * CHUNK;

    const float* xbt = X + (size_t)bt * V * F;            // [256][64] tile
    const float4* xrow4 = reinterpret_cast<const float4*>(xbt + (size_t)i0 * F);
    // xrow4[r*(F/4) + k] = float4 of row i0+r, features 4k..4k+3  (uniform addr)

    __shared__ float wpart[4][CHUNK];      // per-wave partial row sums
    __shared__ float rden[CHUNK];          // reciprocal denominators

    // a -> uniform address, compiler scalarizes to SGPRs
    float af[F];
#pragma unroll
    for (int k = 0; k < F / 4; ++k) {
        const float4 v = reinterpret_cast<const float4*>(A)[k];
        af[4*k+0] = v.x; af[4*k+1] = v.y; af[4*k+2] = v.z; af[4*k+3] = v.w;
    }

    float acc[CHUNK];
#pragma unroll
    for (int r = 0; r < CHUNK; ++r) acc[r] = 0.0f;

    // stream own column in float4 chunks; CHUNK independent fma chains for ILP.
    // f-summation order identical to previous rounds (bit-exact numerics).
    const float4* colp = reinterpret_cast<const float4*>(xbt + (size_t)tid * F);
#pragma unroll
    for (int k = 0; k < F / 4; ++k) {
        const float4 xv = colp[k];
#pragma unroll
        for (int r = 0; r < CHUNK; ++r) {
            const float4 sr = xrow4[r * (F / 4) + k];   // uniform -> s_load_dwordx4
            float s = acc[r];
            s = fmaf(fabsf(xv.x - sr.x), af[4*k+0], s);
            s = fmaf(fabsf(xv.y - sr.y), af[4*k+1], s);
            s = fmaf(fabsf(xv.z - sr.z), af[4*k+2], s);
            s = fmaf(fabsf(xv.w - sr.w), af[4*k+3], s);
            acc[r] = s;
        }
    }

    float tmp[CHUNK];
#pragma unroll
    for (int r = 0; r < CHUNK; ++r)
        tmp[r] = __expf(fmaxf(acc[r], 0.0f));

    // block reduction: row sum = denominator (symmetry)
    const int lane = tid & 63;
    const int wv   = tid >> 6;
#pragma unroll
    for (int r = 0; r < CHUNK; ++r) {
        float v = tmp[r];
        v += __shfl_xor(v, 32);
        v += __shfl_xor(v, 16);
        v += __shfl_xor(v, 8);
        v += __shfl_xor(v, 4);
        v += __shfl_xor(v, 2);
        v += __shfl_xor(v, 1);
        if (lane == 0) wpart[wv][r] = v;
    }
    __syncthreads();
    if (tid < CHUNK) {
        const float d = wpart[0][tid] + wpart[1][tid] + wpart[2][tid] + wpart[3][tid];
        rden[tid] = 1.0f / d;
    }
    __syncthreads();

    // S[bt, i0+r, tid] = tmp[r] / denom[i0+r]; consecutive tids -> coalesced
    float* obase = OUT + (((size_t)bt * V + i0) * V) + tid;
#pragma unroll
    for (int r = 0; r < CHUNK; ++r)
        obase[(size_t)r * V] = tmp[r] * rden[r];
}

extern "C" void kernel_launch(void* const* d_in, const int* in_sizes, int n_in,
                              void* d_out, int out_size, void* d_ws, size_t ws_size,
                              hipStream_t stream)
{
    const float* X = (const float*)d_in[0];   // [B,T,V,F] fp32
    const float* A = (const float*)d_in[1];   // [F,1]     fp32
    float* OUT = (float*)d_out;               // [B,T,V,V] fp32

    dim3 grid(BT * NCHUNK), block(256);
    gl_fused<<<grid, block, 0, stream>>>(X, A, OUT);
}

// Round 6
// 71.680 us; speedup vs baseline: 1.2744x; 1.0078x over previous
//
#include <hip/hip_runtime.h>

// Problem constants (fixed by reference)
constexpr int B = 4, T = 8, V = 256, F = 64;
constexpr int BT = B * T;            // 32 (b,t) slices
constexpr int CHUNK = 8;             // rows of i per block (R3/R5 sweet spot)
constexpr int NCHUNK = V / CHUNK;    // 32 -> grid = 32*32 = 1024 blocks (4 blocks/CU)

typedef float v2f __attribute__((ext_vector_type(2)));

// Block = (bt, 8-row chunk). Thread tid owns column j=tid.
// score(i,j) = sum_f |x_i[f]-x_j[f]|*a[f] is SYMMETRIC, so denom[i]
// (= column-i sum in the reference) equals the row-i sum -> block-local
// reduction, no grid sync / atomics / workspace.
//
// R5: row data via WAVE-UNIFORM global addresses -> s_load_dwordx4 (scalar
// pipe + scalar cache), no LDS staging (88->72 us e2e).
// R6: packed-f32 inner loop. fma(abs(d),a,s) can't pack (VOP3P lacks abs
// modifier) but |d|=max(d,-d) does: v_pk_sub + v_pk_max(neg) + v_pk_fma =
// 3 instr / 2 elems vs 4 -> 25% fewer VALU issues. Each row accumulator is a
// packed pair, horizontally summed once at the end (order change ~1e-7,
// threshold 1.05e-4).
__global__ __launch_bounds__(256)
void gl_fused(const float* __restrict__ X, const float* __restrict__ A,
              float* __restrict__ OUT)
{
    const int tid = threadIdx.x;           // column j
    const int bt  = blockIdx.x / NCHUNK;
    const int ic  = blockIdx.x % NCHUNK;
    const int i0  = ic * CHUNK;

    const float* xbt = X + (size_t)bt * V * F;            // [256][64] tile
    const float4* xrow4 = reinterpret_cast<const float4*>(xbt + (size_t)i0 * F);
    // xrow4[r*(F/4) + k] = float4 of row i0+r, features 4k..4k+3 (uniform addr)

    __shared__ float wpart[4][CHUNK];      // per-wave partial row sums
    __shared__ float rden[CHUNK];          // reciprocal denominators

    // a -> uniform address, scalarized; keep as packed pairs
    v2f af2[F / 2];
#pragma unroll
    for (int k = 0; k < F / 4; ++k) {
        const float4 v = reinterpret_cast<const float4*>(A)[k];
        af2[2*k+0] = (v2f){v.x, v.y};
        af2[2*k+1] = (v2f){v.z, v.w};
    }

    v2f acc2[CHUNK];
#pragma unroll
    for (int r = 0; r < CHUNK; ++r) acc2[r] = (v2f){0.0f, 0.0f};

    // stream own column in float4 chunks; CHUNK independent packed fma chains.
    const float4* colp = reinterpret_cast<const float4*>(xbt + (size_t)tid * F);
#pragma unroll
    for (int k = 0; k < F / 4; ++k) {
        const float4 xv = colp[k];
        const v2f xlo = (v2f){xv.x, xv.y};
        const v2f xhi = (v2f){xv.z, xv.w};
#pragma unroll
        for (int r = 0; r < CHUNK; ++r) {
            const float4 sr = xrow4[r * (F / 4) + k];   // uniform -> s_load_dwordx4
            const v2f d0 = xlo - (v2f){sr.x, sr.y};     // v_pk_add (neg mod)
            const v2f d1 = xhi - (v2f){sr.z, sr.w};
            const v2f a0 = __builtin_elementwise_max(d0, -d0);  // v_pk_max (neg mod)
            const v2f a1 = __builtin_elementwise_max(d1, -d1);
            acc2[r] = __builtin_elementwise_fma(a0, af2[2*k+0], acc2[r]); // v_pk_fma
            acc2[r] = __builtin_elementwise_fma(a1, af2[2*k+1], acc2[r]);
        }
    }

    float tmp[CHUNK];
#pragma unroll
    for (int r = 0; r < CHUNK; ++r) {
        const float s = acc2[r].x + acc2[r].y;
        tmp[r] = __expf(fmaxf(s, 0.0f));
    }

    // block reduction: row sum = denominator (symmetry)
    const int lane = tid & 63;
    const int wv   = tid >> 6;
#pragma unroll
    for (int r = 0; r < CHUNK; ++r) {
        float v = tmp[r];
        v += __shfl_xor(v, 32);
        v += __shfl_xor(v, 16);
        v += __shfl_xor(v, 8);
        v += __shfl_xor(v, 4);
        v += __shfl_xor(v, 2);
        v += __shfl_xor(v, 1);
        if (lane == 0) wpart[wv][r] = v;
    }
    __syncthreads();
    if (tid < CHUNK) {
        const float d = wpart[0][tid] + wpart[1][tid] + wpart[2][tid] + wpart[3][tid];
        rden[tid] = 1.0f / d;
    }
    __syncthreads();

    // S[bt, i0+r, tid] = tmp[r] / denom[i0+r]; consecutive tids -> coalesced
    float* obase = OUT + (((size_t)bt * V + i0) * V) + tid;
#pragma unroll
    for (int r = 0; r < CHUNK; ++r)
        obase[(size_t)r * V] = tmp[r] * rden[r];
}

extern "C" void kernel_launch(void* const* d_in, const int* in_sizes, int n_in,
                              void* d_out, int out_size, void* d_ws, size_t ws_size,
                              hipStream_t stream)
{
    const float* X = (const float*)d_in[0];   // [B,T,V,F] fp32
    const float* A = (const float*)d_in[1];   // [F,1]     fp32
    float* OUT = (float*)d_out;               // [B,T,V,V] fp32

    dim3 grid(BT * NCHUNK), block(256);
    gl_fused<<<grid, block, 0, stream>>>(X, A, OUT);
}